// Round 7
// baseline (200.874 us; speedup 1.0000x reference)
//
#include <hip/hip_runtime.h>
#include <hip/hip_bf16.h>

typedef unsigned int u32;
typedef unsigned short u16;
typedef __attribute__((ext_vector_type(8))) short short8;
typedef __attribute__((ext_vector_type(4))) float f32x4;

#define B_      128
#define N_      4096
#define D_      64
#define K_      8
#define H_      128
#define ITERS_  3
#define NCHUNK  32
#define CHUNK   128
#define SCALE_  0.125f
#define EPS_A   1e-8f
#define EPS_LN  1e-5f

__device__ __forceinline__ float bf_lo(u32 u){ union{u32 v; float f;} x; x.v = u<<16; return x.f; }
__device__ __forceinline__ u16 f2bf(float f){
  union{float f; u32 v;} x; x.f = f;
  u32 v = x.v;
  return (u16)((v + 0x7fffu + ((v>>16)&1u))>>16);   // RNE
}
__device__ __forceinline__ float wsum64(float v){
  #pragma unroll
  for (int off=32; off; off>>=1) v += __shfl_xor(v, off, 64);
  return v;
}
// xtT bank-spread swizzle selector
__device__ __forceinline__ int swT(int d){ return ((d ^ (d>>3)) & 7) << 4; }

// ---- one-time prep: transpose GRU weights; Wqk = Wq @ Wk^T ----
__global__ void prep_t(const float* __restrict__ Wih, const float* __restrict__ Whh,
                       const float* __restrict__ Wq,  const float* __restrict__ Wk,
                       float* __restrict__ WihT, float* __restrict__ WhhT,
                       float* __restrict__ Wqk){
  int t = threadIdx.x;
  if (blockIdx.x < 48){
    int idx = blockIdx.x*256 + t;            // 48*256 = 12288 = 192*64
    int g = idx>>6, d = idx&63;
    WihT[d*192+g] = Wih[idx];
    WhhT[d*192+g] = Whh[idx];
  } else {
    // blocks 48..63: Wqk[a][d] = sum_m Wq[a][m] * Wk[d][m]
    __shared__ float WkL[64*65];
    int bi = blockIdx.x - 48;                // 0..15
    #pragma unroll
    for (int k=0;k<16;++k){
      int idx = t + k*256;
      int d = idx>>6, m = idx&63;
      WkL[m*65+d] = Wk[idx];
    }
    __syncthreads();
    int a = bi*4 + (t>>6), d = t&63;
    float acc = 0.f;
    #pragma unroll 8
    for (int m=0;m<64;++m) acc += Wq[a*64+m]*WkL[m*65+d];
    Wqk[a*64+d] = acc;
  }
}

// ---- slots0 = mu + sigma*noise ; qt = LN(slots0)@Wqk (bf16, padded 16 rows) ----
__global__ __launch_bounds__(512) void slots_init(
    const float* __restrict__ noise, const float* __restrict__ mu, const float* __restrict__ sigma,
    const float* __restrict__ Wqk,
    const float* __restrict__ lnsg, const float* __restrict__ lnsb,
    float* __restrict__ slots, u16* __restrict__ qbuf16){
  int b = blockIdx.x, t = threadIdx.x;
  int i = t>>6, d = t&63;
  __shared__ float svL[K_][68];
  float s0 = mu[d] + sigma[d]*noise[b*512 + t];
  slots[b*512 + t] = s0;
  float m  = wsum64(s0) * (1.f/64.f);
  float df = s0 - m;
  float vv = wsum64(df*df) * (1.f/64.f);
  float sv = df * rsqrtf(vv + EPS_LN) * lnsg[d] + lnsb[d];
  svL[i][d] = sv;
  __syncthreads();
  float qt = 0.f;
  #pragma unroll 8
  for (int dd=0; dd<64; ++dd) qt += svL[i][dd] * Wqk[dd*64 + d];
  qbuf16[b*1024 + t] = f2bf(qt);
  qbuf16[b*1024 + 512 + t] = 0;          // pad rows 8..15
}

// ---- fused: (iter0) LN + dots(MFMA, B from global) + softmax-over-K + PV(MFMA) ----
template<int FUSED>
__global__ __launch_bounds__(256,6) void bigpass(
    const float* __restrict__ inp, u16* __restrict__ xhat,
    const u16* __restrict__ qbuf16,
    const float* __restrict__ lng, const float* __restrict__ lnb,
    float* __restrict__ PU, float* __restrict__ PS){
  int b = blockIdx.y, chunk = blockIdx.x, t = threadIdx.x;
  int w = t>>6, lane = t&63;
  int fr = lane&15, fq = lane>>4;

  // LDS map:
  //  [0,16384)      xtT  [64 d][128 pos] u16, (pos*2) ^ swT(d)   -- dead after phase 2
  //     alias: [0,8704) UL [4][8][68] f32 (written after bar2)
  //  [16384,18432)  qA   [16][64] u16, byte ^ ((row&7)<<4)
  //  [18432,22528)  abuf [4][1024B]
  __shared__ __align__(16) char smem[22528];
  char*  xtT  = smem;
  float* UL   = (float*)smem;
  char*  qA   = smem + 16384;
  char*  abuf = smem + 18432;
  __shared__ float SL[4][8];

  if (t < 128){
    uint4 v = ((const uint4*)(qbuf16 + b*1024))[t];
    int row = t>>3;
    *(uint4*)(qA + ((t*16) ^ ((row&7)<<4))) = v;
  }
  long base = (long)b*N_ + (long)chunk*CHUNK;
  if (FUSED){
    // LN from f32 inputs: 4 threads per row, 2 passes of 64 rows
    #pragma unroll
    for (int p=0;p<2;++p){
      int r = p*64 + (t>>2);
      int q = t&3;
      const float4* xr = (const float4*)(inp + (base + r)*64 + q*16);
      float xv[16]; float s=0.f, sq=0.f;
      #pragma unroll
      for (int c=0;c<4;++c){
        float4 f = xr[c];
        xv[c*4+0]=f.x; xv[c*4+1]=f.y; xv[c*4+2]=f.z; xv[c*4+3]=f.w;
        s  += f.x+f.y+f.z+f.w;
        sq += f.x*f.x+f.y*f.y+f.z*f.z+f.w*f.w;
      }
      s  += __shfl_xor(s, 1, 64);  s  += __shfl_xor(s, 2, 64);
      sq += __shfl_xor(sq, 1, 64); sq += __shfl_xor(sq, 2, 64);
      float mean = s*(1.f/64.f);
      float inv  = rsqrtf(sq*(1.f/64.f) - mean*mean + EPS_LN);
      u32 pk[8];
      #pragma unroll
      for (int e=0;e<8;++e){
        int d0 = q*16 + e*2;
        float a0 = (xv[e*2]  -mean)*inv*lng[d0]   + lnb[d0];
        float a1 = (xv[e*2+1]-mean)*inv*lng[d0+1] + lnb[d0+1];
        pk[e] = (u32)f2bf(a0) | ((u32)f2bf(a1)<<16);
      }
      uint4 v0; v0.x=pk[0]; v0.y=pk[1]; v0.z=pk[2]; v0.w=pk[3];
      uint4 v1; v1.x=pk[4]; v1.y=pk[5]; v1.z=pk[6]; v1.w=pk[7];
      // global xhat (row-major, coalesced) — phase 1 reads it back (L2)
      uint4* gdst = (uint4*)(xhat + (base + r)*64);
      gdst[q*2]   = v0;
      gdst[q*2+1] = v1;
      // xtT (transposed, scalar writes)
      #pragma unroll
      for (int e=0;e<16;++e){
        int d = q*16 + e;
        u16 hv = (e&1) ? (u16)(pk[e>>1]>>16) : (u16)(pk[e>>1]&0xffffu);
        *(u16*)(xtT + d*256 + ((r*2) ^ swT(d))) = hv;
      }
    }
  } else {
    const uint4* gsrc = (const uint4*)(xhat + base*64);
    #pragma unroll
    for (int j=0;j<4;++j){
      int ch = t + j*256;
      uint4 v = gsrc[ch];
      int row = ch>>3, dblk = ch&7;
      u32 wsv[4] = {v.x, v.y, v.z, v.w};
      #pragma unroll
      for (int e2=0;e2<4;++e2){
        #pragma unroll
        for (int h=0;h<2;++h){
          int d = dblk*8 + e2*2 + h;
          u16 hv = h ? (u16)(wsv[e2]>>16) : (u16)(wsv[e2]&0xffffu);
          *(u16*)(xtT + d*256 + ((row*2) ^ swT(d))) = hv;
        }
      }
    }
  }
  __syncthreads();   // bar1: xtT ready; xhat stores drained (vmcnt(0) before barrier)

  // ---- phase 1: dots = mfma(q-tilde, xhat-rows-from-global) -> D[slot][pos] ----
  const char* xg = (const char*)xhat + base*128;
  f32x4 c1[2];
  c1[0] = (f32x4){0.f,0.f,0.f,0.f};
  c1[1] = (f32x4){0.f,0.f,0.f,0.f};
  short8 qf[2];
  #pragma unroll
  for (int kk=0;kk<2;++kk)
    qf[kk] = *(const short8*)(qA + ((fr*128 + kk*64 + fq*16) ^ ((fr&7)<<4)));
  #pragma unroll
  for (int nt=0;nt<2;++nt){
    #pragma unroll
    for (int kk=0;kk<2;++kk){
      int pos = w*32 + nt*16 + fr;
      short8 xf = *(const short8*)(xg + pos*128 + kk*64 + fq*16);
      c1[nt] = __builtin_amdgcn_mfma_f32_16x16x32_bf16(qf[kk], xf, c1[nt], 0, 0, 0);
    }
  }
  // softmax over slots (rows): slot = fq*4+r (valid fq<2), col pos = nt*16+fr
  float tslot[4] = {0.f,0.f,0.f,0.f};
  #pragma unroll
  for (int nt=0;nt<2;++nt){
    float d0 = c1[nt][0]*SCALE_, d1 = c1[nt][1]*SCALE_;
    float d2 = c1[nt][2]*SCALE_, d3 = c1[nt][3]*SCALE_;
    float m = fmaxf(fmaxf(d0,d1), fmaxf(d2,d3));
    m = fmaxf(m, __shfl_xor(m, 16, 64));
    float e0 = __expf(d0-m), e1 = __expf(d1-m), e2 = __expf(d2-m), e3 = __expf(d3-m);
    float sl = e0+e1+e2+e3;
    float inv = 1.f/(sl + __shfl_xor(sl, 16, 64));
    float a0 = e0*inv + EPS_A, a1 = e1*inv + EPS_A;
    float a2 = e2*inv + EPS_A, a3 = e3*inv + EPS_A;
    c1[nt][0]=a0; c1[nt][1]=a1; c1[nt][2]=a2; c1[nt][3]=a3;
    tslot[0]+=a0; tslot[1]+=a1; tslot[2]+=a2; tslot[3]+=a3;
  }
  #pragma unroll
  for (int mk=1; mk<16; mk<<=1){
    tslot[0] += __shfl_xor(tslot[0], mk, 64);
    tslot[1] += __shfl_xor(tslot[1], mk, 64);
    tslot[2] += __shfl_xor(tslot[2], mk, 64);
    tslot[3] += __shfl_xor(tslot[3], mk, 64);
  }
  if (fr==0 && fq<2){
    SL[w][fq*4+0]=tslot[0]; SL[w][fq*4+1]=tslot[1];
    SL[w][fq*4+2]=tslot[2]; SL[w][fq*4+3]=tslot[3];
  }

  // ---- abuf: attn into P-frag order (wave-private region, no barrier needed)
  #pragma unroll
  for (int nt=0;nt<2;++nt){
    #pragma unroll
    for (int r=0;r<4;++r){
      int slot16 = fq*4 + r;
      int lane2  = (nt*2 + (fr>>3))*16 + slot16;
      int j      = fr & 7;
      int byte   = w*1024 + ((lane2*16 + j*2) ^ (((lane2>>3)&7)<<4));
      *(u16*)(abuf + byte) = f2bf(c1[nt][r]);
    }
  }
  // ---- phase 2: U[slot][d] = mfma(attn-frag, xtT-frag) per d-block ----
  short8 pf = *(const short8*)(abuf + w*1024 + ((lane*16) ^ (((lane>>3)&7)<<4)));
  f32x4 c2[4];
  #pragma unroll
  for (int dblk=0;dblk<4;++dblk){
    int d = dblk*16 + fr;
    short8 xtf = *(const short8*)(xtT + d*256 + ((w*64 + fq*16) ^ swT(d)));
    f32x4 z = (f32x4){0.f,0.f,0.f,0.f};
    c2[dblk] = __builtin_amdgcn_mfma_f32_16x16x32_bf16(pf, xtf, z, 0, 0, 0);
  }
  __syncthreads();   // bar2: all xtT reads done -> UL alias safe
  if (fq < 2){
    #pragma unroll
    for (int dblk=0;dblk<4;++dblk){
      #pragma unroll
      for (int r=0;r<4;++r)
        UL[(w*8 + fq*4 + r)*68 + dblk*16 + fr] = c2[dblk][r];
    }
  }
  __syncthreads();   // bar3
  // ---- cross-wave reduce -> PU, PS ----
  {
    int s = t>>6, d = t&63;
    float v0 = UL[(0*8+s)*68+d] + UL[(1*8+s)*68+d] + UL[(2*8+s)*68+d] + UL[(3*8+s)*68+d];
    int s2 = s+4;
    float v1 = UL[(0*8+s2)*68+d] + UL[(1*8+s2)*68+d] + UL[(2*8+s2)*68+d] + UL[(3*8+s2)*68+d];
    long pb = ((long)b*NCHUNK + chunk)*512;
    PU[pb + s*64 + d]  = v0;
    PU[pb + s2*64 + d] = v1;
  }
  if (t < 8)
    PS[((long)b*NCHUNK + chunk)*8 + t] = SL[0][t]+SL[1][t]+SL[2][t]+SL[3][t];
}

// ---- reduce partials; updates = (U/S)@Wv; GRU + LN + MLP; next q-tilde ----
__global__ __launch_bounds__(512) void slot_update(
    const float* __restrict__ PU, const float* __restrict__ PS,
    float* __restrict__ slots,
    const float* __restrict__ WihT, const float* __restrict__ WhhT,
    const float* __restrict__ bih, const float* __restrict__ bhh,
    const float* __restrict__ W1, const float* __restrict__ b1,
    const float* __restrict__ W2, const float* __restrict__ b2,
    const float* __restrict__ lnffg, const float* __restrict__ lnffb,
    const float* __restrict__ lnsg, const float* __restrict__ lnsb,
    const float* __restrict__ Wv, const float* __restrict__ Wqk,
    u16* __restrict__ qbuf16, float* __restrict__ dout, int last){
  int b = blockIdx.x, t = threadIdx.x;
  int i = t>>6, d = t&63;
  __shared__ float updL[K_][68];
  __shared__ float spL[K_][68];
  __shared__ float sfL[K_][68];
  __shared__ float hL[K_][132];
  float u=0.f;
  #pragma unroll 4
  for (int c=0;c<NCHUNK;++c) u += PU[((long)b*NCHUNK + c)*512 + t];
  float S=0.f;
  #pragma unroll 4
  for (int c=0;c<NCHUNK;++c) S += PS[((long)b*NCHUNK + c)*8 + i];
  float ut = u / S;
  float sp = slots[b*512 + t];
  sfL[i][d] = ut;
  spL[i][d] = sp;
  __syncthreads();
  float upd = 0.f;
  #pragma unroll 4
  for (int dd=0; dd<64; ++dd) upd += sfL[i][dd]*Wv[dd*64 + d];
  updL[i][d] = upd;
  __syncthreads();
  float gx0 = bih[d], gx1 = bih[64+d], gx2 = bih[128+d];
  float gh0 = bhh[d], gh1 = bhh[64+d], gh2 = bhh[128+d];
  #pragma unroll 4
  for (int dd=0; dd<64; ++dd){
    float uv = updL[i][dd];
    float sv = spL[i][dd];
    const float* wi = WihT + dd*192 + d;
    const float* wh = WhhT + dd*192 + d;
    gx0 += uv*wi[0]; gx1 += uv*wi[64]; gx2 += uv*wi[128];
    gh0 += sv*wh[0]; gh1 += sv*wh[64]; gh2 += sv*wh[128];
  }
  float rg = 1.f/(1.f+__expf(-(gx0+gh0)));
  float zg = 1.f/(1.f+__expf(-(gx1+gh1)));
  float ng = tanhf(gx2 + rg*gh2);
  float sn = (1.f-zg)*ng + zg*sp;
  float m1 = wsum64(sn)*(1.f/64.f);
  float df = sn-m1;
  float vv = wsum64(df*df)*(1.f/64.f);
  float sf = df*rsqrtf(vv+EPS_LN)*lnffg[d] + lnffb[d];
  sfL[i][d] = sf;
  __syncthreads();
  float h0 = b1[d], h1 = b1[64+d];
  #pragma unroll 4
  for (int dd=0;dd<64;++dd){
    float sv = sfL[i][dd];
    h0 += sv*W1[dd*128 + d];
    h1 += sv*W1[dd*128 + 64 + d];
  }
  h0 = fmaxf(h0, 0.f); h1 = fmaxf(h1, 0.f);
  hL[i][d] = h0; hL[i][d+64] = h1;
  __syncthreads();
  float o = b2[d];
  #pragma unroll 4
  for (int hh=0; hh<128; ++hh) o += hL[i][hh]*W2[hh*64 + d];
  float out = sf + o;
  slots[b*512 + t] = out;
  if (last){
    dout[b*512 + t] = out;
  } else {
    float m2 = wsum64(out)*(1.f/64.f);
    float d2 = out-m2;
    float v2 = wsum64(d2*d2)*(1.f/64.f);
    float sq = d2*rsqrtf(v2+EPS_LN)*lnsg[d] + lnsb[d];
    updL[i][d] = sq;
    __syncthreads();
    float qt=0.f;
    #pragma unroll 8
    for (int dd=0;dd<64;++dd) qt += updL[i][dd]*Wqk[dd*64 + d];
    qbuf16[b*1024 + t] = f2bf(qt);
    qbuf16[b*1024 + 512 + t] = 0;
  }
}

extern "C" void kernel_launch(void* const* d_in, const int* in_sizes, int n_in,
                              void* d_out, int out_size, void* d_ws, size_t ws_size,
                              hipStream_t stream){
  const float* inp   = (const float*)d_in[0];
  const float* noise = (const float*)d_in[1];
  const float* mu    = (const float*)d_in[2];
  const float* sigma = (const float*)d_in[3];
  const float* Wq    = (const float*)d_in[4];
  const float* Wk    = (const float*)d_in[5];
  const float* Wv    = (const float*)d_in[6];
  const float* Wih   = (const float*)d_in[7];
  const float* Whh   = (const float*)d_in[8];
  const float* bih   = (const float*)d_in[9];
  const float* bhh   = (const float*)d_in[10];
  const float* W1    = (const float*)d_in[11];
  const float* b1    = (const float*)d_in[12];
  const float* W2    = (const float*)d_in[13];
  const float* b2    = (const float*)d_in[14];
  const float* lnig  = (const float*)d_in[15];
  const float* lnib  = (const float*)d_in[16];
  const float* lnsg  = (const float*)d_in[17];
  const float* lnsb  = (const float*)d_in[18];
  const float* lnffg = (const float*)d_in[19];
  const float* lnffb = (const float*)d_in[20];
  float* out = (float*)d_out;

  char* ws = (char*)d_ws;
  u16*   xhat   = (u16*)(ws);                      // 67108864 B
  u16*   qbuf16 = (u16*)(ws + 67108864);           // 262144 B
  float* slots  = (float*)(ws + 67371008);         // 262144 B
  float* PU     = (float*)(ws + 67633152);         // 128*32*512*4 = 8388608 B
  float* PS     = (float*)(ws + 76021760);         // 128*32*8*4   = 131072 B
  float* WihT   = (float*)(ws + 76152832);         // 49152 B
  float* WhhT   = (float*)(ws + 76201984);         // 49152 B
  float* Wqk    = (float*)(ws + 76251136);         // 16384 B -> ~76.3 MB total

  prep_t<<<64,256,0,stream>>>(Wih, Whh, Wq, Wk, WihT, WhhT, Wqk);
  slots_init<<<B_,512,0,stream>>>(noise, mu, sigma, Wqk, lnsg, lnsb, slots, qbuf16);
  for (int it=0; it<ITERS_; ++it){
    if (it==0)
      bigpass<1><<<dim3(NCHUNK,B_),256,0,stream>>>(inp, xhat, qbuf16, lnig, lnib, PU, PS);
    else
      bigpass<0><<<dim3(NCHUNK,B_),256,0,stream>>>(inp, xhat, qbuf16, lnig, lnib, PU, PS);
    slot_update<<<B_,512,0,stream>>>(PU, PS, slots, WihT, WhhT, bih, bhh,
                                     W1, b1, W2, b2, lnffg, lnffb, lnsg, lnsb,
                                     Wv, Wqk, qbuf16, out, (it==ITERS_-1)?1:0);
  }
}

// Round 8
// 191.614 us; speedup vs baseline: 1.0483x; 1.0483x over previous
//
#include <hip/hip_runtime.h>
#include <hip/hip_bf16.h>

typedef unsigned int u32;
typedef unsigned short u16;
typedef __attribute__((ext_vector_type(8))) short short8;
typedef __attribute__((ext_vector_type(4))) float f32x4;

#define B_      128
#define N_      4096
#define D_      64
#define K_      8
#define H_      128
#define ITERS_  3
#define NCHUNK  64
#define CHUNK   64
#define SCALE_  0.125f
#define EPS_A   1e-8f
#define EPS_LN  1e-5f

__device__ __forceinline__ float bf_lo(u32 u){ union{u32 v; float f;} x; x.v = u<<16; return x.f; }
__device__ __forceinline__ u16 f2bf(float f){
  union{float f; u32 v;} x; x.f = f;
  u32 v = x.v;
  return (u16)((v + 0x7fffu + ((v>>16)&1u))>>16);   // RNE
}
__device__ __forceinline__ float wsum64(float v){
  #pragma unroll
  for (int off=32; off; off>>=1) v += __shfl_xor(v, off, 64);
  return v;
}
// xtT bank-spread swizzle selector (flips 16B-granule within a 128B row)
__device__ __forceinline__ int swT(int d){ return ((d ^ (d>>3)) & 7) << 4; }

// ---- one-time prep: transpose GRU weights; Wqk = Wq @ Wk^T ----
__global__ void prep_t(const float* __restrict__ Wih, const float* __restrict__ Whh,
                       const float* __restrict__ Wq,  const float* __restrict__ Wk,
                       float* __restrict__ WihT, float* __restrict__ WhhT,
                       float* __restrict__ Wqk){
  int t = threadIdx.x;
  if (blockIdx.x < 48){
    int idx = blockIdx.x*256 + t;            // 48*256 = 12288 = 192*64
    int g = idx>>6, d = idx&63;
    WihT[d*192+g] = Wih[idx];
    WhhT[d*192+g] = Whh[idx];
  } else {
    __shared__ float WkL[64*65];
    int bi = blockIdx.x - 48;                // 0..15
    #pragma unroll
    for (int k=0;k<16;++k){
      int idx = t + k*256;
      int d = idx>>6, m = idx&63;
      WkL[m*65+d] = Wk[idx];
    }
    __syncthreads();
    int a = bi*4 + (t>>6), d = t&63;
    float acc = 0.f;
    #pragma unroll 8
    for (int m=0;m<64;++m) acc += Wq[a*64+m]*WkL[m*65+d];
    Wqk[a*64+d] = acc;
  }
}

// ---- slots0 = mu + sigma*noise ; qt = LN(slots0)@Wqk (bf16, padded 16 rows) ----
__global__ __launch_bounds__(512) void slots_init(
    const float* __restrict__ noise, const float* __restrict__ mu, const float* __restrict__ sigma,
    const float* __restrict__ Wqk,
    const float* __restrict__ lnsg, const float* __restrict__ lnsb,
    float* __restrict__ slots, u16* __restrict__ qbuf16){
  int b = blockIdx.x, t = threadIdx.x;
  int i = t>>6, d = t&63;
  __shared__ float svL[K_][68];
  float s0 = mu[d] + sigma[d]*noise[b*512 + t];
  slots[b*512 + t] = s0;
  float m  = wsum64(s0) * (1.f/64.f);
  float df = s0 - m;
  float vv = wsum64(df*df) * (1.f/64.f);
  float sv = df * rsqrtf(vv + EPS_LN) * lnsg[d] + lnsb[d];
  svL[i][d] = sv;
  __syncthreads();
  float qt = 0.f;
  #pragma unroll 8
  for (int dd=0; dd<64; ++dd) qt += svL[i][dd] * Wqk[dd*64 + d];
  qbuf16[b*1024 + t] = f2bf(qt);
  qbuf16[b*1024 + 512 + t] = 0;          // pad rows 8..15
}

// ---- fused: (iter0) LN + dots(MFMA) + softmax-over-K + PV(MFMA) partials ----
// CHUNK=64: per block 64 positions; per wave 16 pos in phase 1; phase 2 split
// as (pos-half = w>>1, d-half = w&1) so the K=32 contraction spans 32 pos.
template<int FUSED>
__global__ __launch_bounds__(256,7) void bigpass(
    const float* __restrict__ inp, u16* __restrict__ xhat,
    const u16* __restrict__ qbuf16,
    const float* __restrict__ lng, const float* __restrict__ lnb,
    float* __restrict__ PU, float* __restrict__ PS){
  int b = blockIdx.y, chunk = blockIdx.x, t = threadIdx.x;
  int w = t>>6, lane = t&63;
  int fr = lane&15, fq = lane>>4;

  // LDS map:
  //  [0,8192)       xt   [64 pos][64 d] u16, byte ^ ((pos&7)<<4) -- dead after ph1
  //     alias: [0,4352) UL [16][68] f32 (written after bar2/ph2)
  //  [8192,16384)   xtT  [64 d][64 pos] u16, d*128 + (pos*2 ^ swT(d))
  //  [16384,18432)  qA   [16][64] u16, byte ^ ((row&7)<<4)
  //  [18432,20480)  abuf 2 halves x 1024B (attn in A-frag order)
  __shared__ __align__(16) char smem[20480];
  char*  xt   = smem;
  float* UL   = (float*)smem;
  char*  xtT  = smem + 8192;
  char*  qA   = smem + 16384;
  char*  abuf = smem + 18432;
  __shared__ float SL[4][8];

  if (t < 128){
    uint4 v = ((const uint4*)(qbuf16 + b*1024))[t];
    int row = t>>3;
    *(uint4*)(qA + ((t*16) ^ ((row&7)<<4))) = v;
  }
  long base = (long)b*N_ + (long)chunk*CHUNK;
  if (FUSED){
    // LN from f32 inputs: 4 threads per row, 64 rows
    int r = t>>2, q = t&3;
    const float4* xr = (const float4*)(inp + (base + r)*64 + q*16);
    float xv[16]; float s=0.f, sq=0.f;
    #pragma unroll
    for (int c=0;c<4;++c){
      float4 f = xr[c];
      xv[c*4+0]=f.x; xv[c*4+1]=f.y; xv[c*4+2]=f.z; xv[c*4+3]=f.w;
      s  += f.x+f.y+f.z+f.w;
      sq += f.x*f.x+f.y*f.y+f.z*f.z+f.w*f.w;
    }
    s  += __shfl_xor(s, 1, 64);  s  += __shfl_xor(s, 2, 64);
    sq += __shfl_xor(sq, 1, 64); sq += __shfl_xor(sq, 2, 64);
    float mean = s*(1.f/64.f);
    float inv  = rsqrtf(sq*(1.f/64.f) - mean*mean + EPS_LN);
    u32 pk[8];
    #pragma unroll
    for (int e=0;e<8;++e){
      int d0 = q*16 + e*2;
      float a0 = (xv[e*2]  -mean)*inv*lng[d0]   + lnb[d0];
      float a1 = (xv[e*2+1]-mean)*inv*lng[d0+1] + lnb[d0+1];
      pk[e] = (u32)f2bf(a0) | ((u32)f2bf(a1)<<16);
    }
    uint4 v0; v0.x=pk[0]; v0.y=pk[1]; v0.z=pk[2]; v0.w=pk[3];
    uint4 v1; v1.x=pk[4]; v1.y=pk[5]; v1.z=pk[6]; v1.w=pk[7];
    // global xhat (coalesced; NOT read back this pass)
    uint4* gdst = (uint4*)(xhat + (base + r)*64);
    gdst[q*2]   = v0;
    gdst[q*2+1] = v1;
    // xt (row-major swizzled)
    int byte0 = r*128 + q*32;
    *(uint4*)(xt + ( byte0      ^ ((r&7)<<4))) = v0;
    *(uint4*)(xt + ((byte0+16)  ^ ((r&7)<<4))) = v1;
    // xtT (transposed, scalar writes)
    #pragma unroll
    for (int e=0;e<16;++e){
      int d = q*16 + e;
      u16 hv = (e&1) ? (u16)(pk[e>>1]>>16) : (u16)(pk[e>>1]&0xffffu);
      *(u16*)(xtT + d*128 + ((r*2) ^ swT(d)));
      *(u16*)(xtT + d*128 + ((r*2) ^ swT(d))) = hv;
    }
  } else {
    const uint4* gsrc = (const uint4*)(xhat + base*64);
    #pragma unroll
    for (int j=0;j<2;++j){
      int ch = t + j*256;
      uint4 v = gsrc[ch];
      int row = ch>>3, dblk = ch&7;
      *(uint4*)(xt + ((ch*16) ^ ((row&7)<<4))) = v;
      u32 wsv[4] = {v.x, v.y, v.z, v.w};
      #pragma unroll
      for (int e2=0;e2<4;++e2){
        #pragma unroll
        for (int h=0;h<2;++h){
          int d = dblk*8 + e2*2 + h;
          u16 hv = h ? (u16)(wsv[e2]>>16) : (u16)(wsv[e2]&0xffffu);
          *(u16*)(xtT + d*128 + ((row*2) ^ swT(d))) = hv;
        }
      }
    }
  }
  __syncthreads();   // bar1: xt/xtT/qA ready

  // ---- phase 1: dots = mfma(q-tilde, x-rows) -> D[slot][pos], 16 pos/wave ----
  f32x4 c1 = (f32x4){0.f,0.f,0.f,0.f};
  #pragma unroll
  for (int kk=0;kk<2;++kk){
    short8 qf = *(const short8*)(qA + ((fr*128 + kk*64 + fq*16) ^ ((fr&7)<<4)));
    int pos = w*16 + fr;
    short8 xf = *(const short8*)(xt + ((pos*128 + kk*64 + fq*16) ^ ((pos&7)<<4)));
    c1 = __builtin_amdgcn_mfma_f32_16x16x32_bf16(qf, xf, c1, 0, 0, 0);
  }
  // softmax over slots: slot = fq*4+r (valid fq<2; rows 8..15 are zero-pad junk)
  {
    float d0 = c1[0]*SCALE_, d1 = c1[1]*SCALE_;
    float d2 = c1[2]*SCALE_, d3 = c1[3]*SCALE_;
    float m = fmaxf(fmaxf(d0,d1), fmaxf(d2,d3));
    m = fmaxf(m, __shfl_xor(m, 16, 64));
    float e0 = __expf(d0-m), e1 = __expf(d1-m), e2 = __expf(d2-m), e3 = __expf(d3-m);
    float sl = e0+e1+e2+e3;
    float inv = 1.f/(sl + __shfl_xor(sl, 16, 64));
    c1[0] = e0*inv + EPS_A; c1[1] = e1*inv + EPS_A;
    c1[2] = e2*inv + EPS_A; c1[3] = e3*inv + EPS_A;
    float t0=c1[0], t1=c1[1], t2=c1[2], t3=c1[3];
    #pragma unroll
    for (int mk=1; mk<16; mk<<=1){
      t0 += __shfl_xor(t0, mk, 64);
      t1 += __shfl_xor(t1, mk, 64);
      t2 += __shfl_xor(t2, mk, 64);
      t3 += __shfl_xor(t3, mk, 64);
    }
    if (fr==0 && fq<2){
      SL[w][fq*4+0]=t0; SL[w][fq*4+1]=t1;
      SL[w][fq*4+2]=t2; SL[w][fq*4+3]=t3;
    }
  }
  // abuf: attn into A-frag order. half h=w>>1, k-offset (w&1)*16.
  // lane2 = (k>>3)*16 + slot ; j = k&7 ; k = (w&1)*16 + fr
  #pragma unroll
  for (int r=0;r<4;++r){
    int slot16 = fq*4 + r;
    int lane2  = ((w&1)*2 + (fr>>3))*16 + slot16;
    int j      = fr & 7;
    int byte   = (w>>1)*1024 + ((lane2*16 + j*2) ^ (((lane2>>3)&7)<<4));
    *(u16*)(abuf + byte) = f2bf(c1[r]);
  }
  __syncthreads();   // bar2: abuf complete (cross-wave); xt dead -> UL alias ok after ph2

  // ---- phase 2: wave w -> pos-half h=w>>1, d-half w&1 ----
  {
    int h = w>>1;
    short8 pf = *(const short8*)(abuf + h*1024 + ((lane*16) ^ (((lane>>3)&7)<<4)));
    f32x4 c2[2];
    #pragma unroll
    for (int dblk=0;dblk<2;++dblk){
      int d = (w&1)*32 + dblk*16 + fr;
      short8 xtf = *(const short8*)(xtT + d*128 + ((h*64 + fq*16) ^ swT(d)));
      f32x4 z = (f32x4){0.f,0.f,0.f,0.f};
      c2[dblk] = __builtin_amdgcn_mfma_f32_16x16x32_bf16(pf, xtf, z, 0, 0, 0);
    }
    // UL rows = h*8 + slot (slot=fq*4+r, fq<2), cols = (w&1)*32 + dblk*16 + fr
    if (fq < 2){
      #pragma unroll
      for (int dblk=0;dblk<2;++dblk){
        #pragma unroll
        for (int r=0;r<4;++r)
          UL[(h*8 + fq*4 + r)*68 + (w&1)*32 + dblk*16 + fr] = c2[dblk][r];
      }
    }
  }
  __syncthreads();   // bar3
  // ---- cross-half reduce -> PU, PS ----
  {
    int s = t>>6, d = t&63;
    float v0 = UL[(s)*68+d]   + UL[(8+s)*68+d];
    float v1 = UL[(s+4)*68+d] + UL[(12+s)*68+d];
    long pb = ((long)b*NCHUNK + chunk)*512;
    PU[pb + s*64 + d]     = v0;
    PU[pb + (s+4)*64 + d] = v1;
  }
  if (t < 8)
    PS[((long)b*NCHUNK + chunk)*8 + t] = SL[0][t]+SL[1][t]+SL[2][t]+SL[3][t];
}

// ---- reduce partials; updates = (U/S)@Wv; GRU + LN + MLP; next q-tilde ----
__global__ __launch_bounds__(512) void slot_update(
    const float* __restrict__ PU, const float* __restrict__ PS,
    float* __restrict__ slots,
    const float* __restrict__ WihT, const float* __restrict__ WhhT,
    const float* __restrict__ bih, const float* __restrict__ bhh,
    const float* __restrict__ W1, const float* __restrict__ b1,
    const float* __restrict__ W2, const float* __restrict__ b2,
    const float* __restrict__ lnffg, const float* __restrict__ lnffb,
    const float* __restrict__ lnsg, const float* __restrict__ lnsb,
    const float* __restrict__ Wv, const float* __restrict__ Wqk,
    u16* __restrict__ qbuf16, float* __restrict__ dout, int last){
  int b = blockIdx.x, t = threadIdx.x;
  int i = t>>6, d = t&63;
  __shared__ float updL[K_][68];
  __shared__ float spL[K_][68];
  __shared__ float sfL[K_][68];
  __shared__ float hL[K_][132];
  float u=0.f;
  #pragma unroll 4
  for (int c=0;c<NCHUNK;++c) u += PU[((long)b*NCHUNK + c)*512 + t];
  float S=0.f;
  #pragma unroll 4
  for (int c=0;c<NCHUNK;++c) S += PS[((long)b*NCHUNK + c)*8 + i];
  float ut = u / S;
  float sp = slots[b*512 + t];
  sfL[i][d] = ut;
  spL[i][d] = sp;
  __syncthreads();
  float upd = 0.f;
  #pragma unroll 4
  for (int dd=0; dd<64; ++dd) upd += sfL[i][dd]*Wv[dd*64 + d];
  updL[i][d] = upd;
  __syncthreads();
  float gx0 = bih[d], gx1 = bih[64+d], gx2 = bih[128+d];
  float gh0 = bhh[d], gh1 = bhh[64+d], gh2 = bhh[128+d];
  #pragma unroll 4
  for (int dd=0; dd<64; ++dd){
    float uv = updL[i][dd];
    float sv = spL[i][dd];
    const float* wi = WihT + dd*192 + d;
    const float* wh = WhhT + dd*192 + d;
    gx0 += uv*wi[0]; gx1 += uv*wi[64]; gx2 += uv*wi[128];
    gh0 += sv*wh[0]; gh1 += sv*wh[64]; gh2 += sv*wh[128];
  }
  float rg = 1.f/(1.f+__expf(-(gx0+gh0)));
  float zg = 1.f/(1.f+__expf(-(gx1+gh1)));
  float ng = tanhf(gx2 + rg*gh2);
  float sn = (1.f-zg)*ng + zg*sp;
  float m1 = wsum64(sn)*(1.f/64.f);
  float df = sn-m1;
  float vv = wsum64(df*df)*(1.f/64.f);
  float sf = df*rsqrtf(vv+EPS_LN)*lnffg[d] + lnffb[d];
  sfL[i][d] = sf;
  __syncthreads();
  float h0 = b1[d], h1 = b1[64+d];
  #pragma unroll 4
  for (int dd=0;dd<64;++dd){
    float sv = sfL[i][dd];
    h0 += sv*W1[dd*128 + d];
    h1 += sv*W1[dd*128 + 64 + d];
  }
  h0 = fmaxf(h0, 0.f); h1 = fmaxf(h1, 0.f);
  hL[i][d] = h0; hL[i][d+64] = h1;
  __syncthreads();
  float o = b2[d];
  #pragma unroll 4
  for (int hh=0; hh<128; ++hh) o += hL[i][hh]*W2[hh*64 + d];
  float out = sf + o;
  slots[b*512 + t] = out;
  if (last){
    dout[b*512 + t] = out;
  } else {
    float m2 = wsum64(out)*(1.f/64.f);
    float d2 = out-m2;
    float v2 = wsum64(d2*d2)*(1.f/64.f);
    float sq = d2*rsqrtf(v2+EPS_LN)*lnsg[d] + lnsb[d];
    updL[i][d] = sq;
    __syncthreads();
    float qt=0.f;
    #pragma unroll 8
    for (int dd=0;dd<64;++dd) qt += updL[i][dd]*Wqk[dd*64 + d];
    qbuf16[b*1024 + t] = f2bf(qt);
    qbuf16[b*1024 + 512 + t] = 0;
  }
}

extern "C" void kernel_launch(void* const* d_in, const int* in_sizes, int n_in,
                              void* d_out, int out_size, void* d_ws, size_t ws_size,
                              hipStream_t stream){
  const float* inp   = (const float*)d_in[0];
  const float* noise = (const float*)d_in[1];
  const float* mu    = (const float*)d_in[2];
  const float* sigma = (const float*)d_in[3];
  const float* Wq    = (const float*)d_in[4];
  const float* Wk    = (const float*)d_in[5];
  const float* Wv    = (const float*)d_in[6];
  const float* Wih   = (const float*)d_in[7];
  const float* Whh   = (const float*)d_in[8];
  const float* bih   = (const float*)d_in[9];
  const float* bhh   = (const float*)d_in[10];
  const float* W1    = (const float*)d_in[11];
  const float* b1    = (const float*)d_in[12];
  const float* W2    = (const float*)d_in[13];
  const float* b2    = (const float*)d_in[14];
  const float* lnig  = (const float*)d_in[15];
  const float* lnib  = (const float*)d_in[16];
  const float* lnsg  = (const float*)d_in[17];
  const float* lnsb  = (const float*)d_in[18];
  const float* lnffg = (const float*)d_in[19];
  const float* lnffb = (const float*)d_in[20];
  float* out = (float*)d_out;

  char* ws = (char*)d_ws;
  u16*   xhat   = (u16*)(ws);                      // 67108864 B
  u16*   qbuf16 = (u16*)(ws + 67108864);           // 262144 B
  float* slots  = (float*)(ws + 67371008);         // 262144 B
  float* PU     = (float*)(ws + 67633152);         // 128*64*512*4 = 16777216 B
  float* PS     = (float*)(ws + 84410368);         // 128*64*8*4   = 262144 B
  float* WihT   = (float*)(ws + 84672512);         // 49152 B
  float* WhhT   = (float*)(ws + 84721664);         // 49152 B
  float* Wqk    = (float*)(ws + 84770816);         // 16384 B -> ~84.8 MB total

  prep_t<<<64,256,0,stream>>>(Wih, Whh, Wq, Wk, WihT, WhhT, Wqk);
  slots_init<<<B_,512,0,stream>>>(noise, mu, sigma, Wqk, lnsg, lnsb, slots, qbuf16);
  for (int it=0; it<ITERS_; ++it){
    if (it==0)
      bigpass<1><<<dim3(NCHUNK,B_),256,0,stream>>>(inp, xhat, qbuf16, lnig, lnib, PU, PS);
    else
      bigpass<0><<<dim3(NCHUNK,B_),256,0,stream>>>(inp, xhat, qbuf16, lnig, lnib, PU, PS);
    slot_update<<<B_,512,0,stream>>>(PU, PS, slots, WihT, WhhT, bih, bhh,
                                     W1, b1, W2, b2, lnffg, lnffb, lnsg, lnsb,
                                     Wv, Wqk, qbuf16, out, (it==ITERS_-1)?1:0);
  }
}

// Round 9
// 186.460 us; speedup vs baseline: 1.0773x; 1.0276x over previous
//
#include <hip/hip_runtime.h>
#include <hip/hip_bf16.h>

typedef unsigned int u32;
typedef unsigned short u16;
typedef __attribute__((ext_vector_type(8))) short short8;
typedef __attribute__((ext_vector_type(4))) float f32x4;
typedef __attribute__((ext_vector_type(2))) u32 u32x2;

#define B_      128
#define N_      4096
#define K_      8
#define ITERS_  3
#define OC_     8        // PU output chunks per batch
#define CPB_    4        // chunks per block
#define CHUNK   128
#define SCALE_  0.125f
#define EPS_A   1e-8f
#define EPS_LN  1e-5f

__device__ __forceinline__ float bf_lo(u32 u){ union{u32 v; float f;} x; x.v = u<<16; return x.f; }
__device__ __forceinline__ u16 f2bf(float f){
  union{float f; u32 v;} x; x.f = f;
  u32 v = x.v;
  return (u16)((v + 0x7fffu + ((v>>16)&1u))>>16);   // RNE
}
__device__ __forceinline__ float wsum64(float v){
  #pragma unroll
  for (int off=32; off; off>>=1) v += __shfl_xor(v, off, 64);
  return v;
}

// ---- one-time prep: transpose GRU weights; Wqk = Wq @ Wk^T ----
__global__ void prep_t(const float* __restrict__ Wih, const float* __restrict__ Whh,
                       const float* __restrict__ Wq,  const float* __restrict__ Wk,
                       float* __restrict__ WihT, float* __restrict__ WhhT,
                       float* __restrict__ Wqk){
  int t = threadIdx.x;
  if (blockIdx.x < 48){
    int idx = blockIdx.x*256 + t;            // 12288 = 192*64
    int g = idx>>6, d = idx&63;
    WihT[d*192+g] = Wih[idx];
    WhhT[d*192+g] = Whh[idx];
  } else {
    __shared__ float WkL[64*65];
    int bi = blockIdx.x - 48;                // 0..15
    #pragma unroll
    for (int k=0;k<16;++k){
      int idx = t + k*256;
      int d = idx>>6, m = idx&63;
      WkL[m*65+d] = Wk[idx];
    }
    __syncthreads();
    int a = bi*4 + (t>>6), d = t&63;
    float acc = 0.f;
    #pragma unroll 8
    for (int m=0;m<64;++m) acc += Wq[a*64+m]*WkL[m*65+d];
    Wqk[a*64+d] = acc;
  }
}

// ---- slots0 = mu + sigma*noise ; qt = LN(slots0)@Wqk (bf16, padded 16 rows) ----
__global__ __launch_bounds__(512) void slots_init(
    const float* __restrict__ noise, const float* __restrict__ mu, const float* __restrict__ sigma,
    const float* __restrict__ Wqk,
    const float* __restrict__ lnsg, const float* __restrict__ lnsb,
    float* __restrict__ slots, u16* __restrict__ qbuf16){
  int b = blockIdx.x, t = threadIdx.x;
  int i = t>>6, d = t&63;
  __shared__ float svL[K_][68];
  float s0 = mu[d] + sigma[d]*noise[b*512 + t];
  slots[b*512 + t] = s0;
  float m  = wsum64(s0) * (1.f/64.f);
  float df = s0 - m;
  float vv = wsum64(df*df) * (1.f/64.f);
  float sv = df * rsqrtf(vv + EPS_LN) * lnsg[d] + lnsb[d];
  svL[i][d] = sv;
  __syncthreads();
  float qt = 0.f;
  #pragma unroll 8
  for (int dd=0; dd<64; ++dd) qt += svL[i][dd] * Wqk[dd*64 + d];
  qbuf16[b*1024 + t] = f2bf(qt);
  qbuf16[b*1024 + 512 + t] = 0;          // pad rows 8..15
}

// ---- pipelined bigpass: 4 chunks/block, dots(MFMA) + softmax + PV(MFMA via tr-reads) ----
// xs subtiled frag layout (per 32-pos x 64-d block, elem (p,d)):
// byte = (p>>5)<<12 | (d>>4)<<10 | ((p>>2)&1)<<9 | ((p>>3)&3)<<7 | (p&3)<<5 | (d&15)*2
template<int FUSED>
__global__ __launch_bounds__(256,4) void bigpass(
    const float* __restrict__ inp, u16* __restrict__ xhat,
    const u16* __restrict__ qbuf16,
    const float* __restrict__ lng, const float* __restrict__ lnb,
    float* __restrict__ PU, float* __restrict__ PS){
  int b = blockIdx.y, oc = blockIdx.x, t = threadIdx.x;
  int w = t>>6, lane = t&63;
  int fr = lane&15, fq = lane>>4;

  // LDS: [0,32768) xs dbuf 2x16KB ; [32768,34816) qA ; [34816,38912) abuf
  __shared__ __align__(16) char smem[38912];
  char* qA   = smem + 32768;
  char* abuf = smem + 34816;
  __shared__ float SL[4][8];
  u32 smb = (u32)(size_t)smem;

  if (t < 128){
    uint4 v = ((const uint4*)(qbuf16 + b*1024))[t];
    int row = t>>3;
    *(uint4*)(qA + ((t*16) ^ ((row&7)<<4))) = v;
  }
  long base_pos = (long)b*N_ + (long)oc*(CPB_*CHUNK);

  short8 qf0, qf1;
  f32x4 c2 = (f32x4){0.f,0.f,0.f,0.f};
  float tsl[4] = {0.f,0.f,0.f,0.f};

  float lg[16], lb[16];
  if (FUSED){
    int q = t&3;
    #pragma unroll
    for (int e=0;e<16;++e){ lg[e] = lng[q*16+e]; lb[e] = lnb[q*16+e]; }
  }

  uint4 stv[2][4];
  if (!FUSED){
    const uint4* g0 = (const uint4*)(xhat + base_pos*64);
    #pragma unroll
    for (int j=0;j<4;++j) stv[0][j] = g0[t + j*256];
  }

  #pragma unroll
  for (int cc=0; cc<CPB_; ++cc){
    int buf = cc&1;
    if (!FUSED){
      if (cc+1 < CPB_){
        const uint4* gn = (const uint4*)(xhat + (base_pos + (long)(cc+1)*CHUNK)*64);
        #pragma unroll
        for (int j=0;j<4;++j) stv[(cc+1)&1][j] = gn[t + j*256];
      }
      #pragma unroll
      for (int j=0;j<4;++j){
        int ch = t + j*256;
        int p = ch>>3, g = ch&7;
        int byte = ((p>>5)<<12) | ((g>>1)<<10) | (((p>>2)&1)<<9)
                 | (((p>>3)&3)<<7) | ((p&3)<<5) | ((g&1)<<4);
        *(uint4*)(smem + buf*16384 + byte) = stv[buf][j];
      }
    } else {
      #pragma unroll
      for (int p2=0;p2<2;++p2){
        int r = p2*64 + (t>>2), q = t&3;
        const float4* xr = (const float4*)(inp + (base_pos + (long)cc*CHUNK + r)*64 + q*16);
        float xv[16]; float s=0.f, sq=0.f;
        #pragma unroll
        for (int c=0;c<4;++c){
          float4 f = xr[c];
          xv[c*4+0]=f.x; xv[c*4+1]=f.y; xv[c*4+2]=f.z; xv[c*4+3]=f.w;
          s  += f.x+f.y+f.z+f.w;
          sq += f.x*f.x+f.y*f.y+f.z*f.z+f.w*f.w;
        }
        s  += __shfl_xor(s,1,64);  s  += __shfl_xor(s,2,64);
        sq += __shfl_xor(sq,1,64); sq += __shfl_xor(sq,2,64);
        float mean = s*(1.f/64.f);
        float inv  = rsqrtf(sq*(1.f/64.f) - mean*mean + EPS_LN);
        u32 pk[8];
        #pragma unroll
        for (int e=0;e<8;++e){
          float a0 = (xv[e*2]  -mean)*inv*lg[e*2]   + lb[e*2];
          float a1 = (xv[e*2+1]-mean)*inv*lg[e*2+1] + lb[e*2+1];
          pk[e] = (u32)f2bf(a0) | ((u32)f2bf(a1)<<16);
        }
        uint4 v0; v0.x=pk[0]; v0.y=pk[1]; v0.z=pk[2]; v0.w=pk[3];
        uint4 v1; v1.x=pk[4]; v1.y=pk[5]; v1.z=pk[6]; v1.w=pk[7];
        uint4* gdst = (uint4*)(xhat + (base_pos + (long)cc*CHUNK + r)*64);
        gdst[q*2]   = v0;
        gdst[q*2+1] = v1;
        int byte0 = ((r>>5)<<12) | (q<<10) | (((r>>2)&1)<<9) | (((r>>3)&3)<<7) | ((r&3)<<5);
        *(uint4*)(smem + buf*16384 + byte0)      = v0;
        *(uint4*)(smem + buf*16384 + byte0 + 16) = v1;
      }
    }
    __syncthreads();   // bar1: xs[buf] ready; prev ph2 drained
    if (cc==0){
      qf0 = *(const short8*)(qA + ((fr*128 +  0 + fq*16) ^ ((fr&7)<<4)));
      qf1 = *(const short8*)(qA + ((fr*128 + 64 + fq*16) ^ ((fr&7)<<4)));
    }
    // ---- phase 1: dots[16 slots][32 pos per wave] ----
    f32x4 c1[2];
    #pragma unroll
    for (int nt=0;nt<2;++nt){
      c1[nt] = (f32x4){0.f,0.f,0.f,0.f};
      #pragma unroll
      for (int kk=0;kk<2;++kk){
        int byte = (w<<12) | ((kk*2+(fq>>1))<<10) | (((fr>>2)&1)<<9)
                 | ((nt*2+(fr>>3))<<7) | ((fr&3)<<5) | ((fq&1)<<4);
        short8 xf = *(const short8*)(smem + buf*16384 + byte);
        c1[nt] = __builtin_amdgcn_mfma_f32_16x16x32_bf16(kk?qf1:qf0, xf, c1[nt], 0,0,0);
      }
    }
    // softmax over slots + abuf write (attn row-major [slot][pos], slot-row swizzled)
    #pragma unroll
    for (int nt=0;nt<2;++nt){
      float d0 = c1[nt][0]*SCALE_, d1 = c1[nt][1]*SCALE_;
      float d2 = c1[nt][2]*SCALE_, d3 = c1[nt][3]*SCALE_;
      float m = fmaxf(fmaxf(d0,d1), fmaxf(d2,d3));
      m = fmaxf(m, __shfl_xor(m, 16, 64));
      float e0 = __expf(d0-m), e1 = __expf(d1-m), e2 = __expf(d2-m), e3 = __expf(d3-m);
      float sl = e0+e1+e2+e3;
      float inv = 1.f/(sl + __shfl_xor(sl, 16, 64));
      float a0 = e0*inv + EPS_A, a1 = e1*inv + EPS_A;
      float a2 = e2*inv + EPS_A, a3 = e3*inv + EPS_A;
      tsl[0]+=a0; tsl[1]+=a1; tsl[2]+=a2; tsl[3]+=a3;
      int pos2 = w*64 + nt*32 + fr*2;
      #pragma unroll
      for (int r=0;r<4;++r){
        int slot = fq*4 + r;
        float av = (r==0)?a0:((r==1)?a1:((r==2)?a2:a3));
        int byteA = ((slot<<8) + pos2) ^ ((slot&7)<<4);
        *(u16*)(abuf + byteA) = f2bf(av);
      }
    }
    __syncthreads();   // bar2: abuf complete
    // ---- phase 2: wave w owns d-tile w; accumulate over 128 pos ----
    {
      u32 va = smb + buf*16384 + (w<<10) + (fq<<7) + (fr<<1);
      u32x2 tv0,tv1,tv2,tv3,tv4,tv5,tv6,tv7;
      asm volatile("ds_read_b64_tr_b16 %0, %1 offset:0"     : "=v"(tv0) : "v"(va));
      asm volatile("ds_read_b64_tr_b16 %0, %1 offset:512"   : "=v"(tv1) : "v"(va));
      asm volatile("ds_read_b64_tr_b16 %0, %1 offset:4096"  : "=v"(tv2) : "v"(va));
      asm volatile("ds_read_b64_tr_b16 %0, %1 offset:4608"  : "=v"(tv3) : "v"(va));
      asm volatile("ds_read_b64_tr_b16 %0, %1 offset:8192"  : "=v"(tv4) : "v"(va));
      asm volatile("ds_read_b64_tr_b16 %0, %1 offset:8704"  : "=v"(tv5) : "v"(va));
      asm volatile("ds_read_b64_tr_b16 %0, %1 offset:12288" : "=v"(tv6) : "v"(va));
      asm volatile("ds_read_b64_tr_b16 %0, %1 offset:12800" : "=v"(tv7) : "v"(va));
      short8 pa[4];
      #pragma unroll
      for (int k2=0;k2<4;++k2){
        int byteP = (fr<<8) + ((k2*64 + fq*16) ^ ((fr&7)<<4));
        pa[k2] = *(const short8*)(abuf + byteP);
      }
      asm volatile("s_waitcnt lgkmcnt(0)" ::: "memory");
      __builtin_amdgcn_sched_barrier(0);
      union { short8 s8; u32 u4[4]; } xb;
      xb.u4[0]=tv0.x; xb.u4[1]=tv0.y; xb.u4[2]=tv1.x; xb.u4[3]=tv1.y;
      c2 = __builtin_amdgcn_mfma_f32_16x16x32_bf16(pa[0], xb.s8, c2, 0,0,0);
      xb.u4[0]=tv2.x; xb.u4[1]=tv2.y; xb.u4[2]=tv3.x; xb.u4[3]=tv3.y;
      c2 = __builtin_amdgcn_mfma_f32_16x16x32_bf16(pa[1], xb.s8, c2, 0,0,0);
      xb.u4[0]=tv4.x; xb.u4[1]=tv4.y; xb.u4[2]=tv5.x; xb.u4[3]=tv5.y;
      c2 = __builtin_amdgcn_mfma_f32_16x16x32_bf16(pa[2], xb.s8, c2, 0,0,0);
      xb.u4[0]=tv6.x; xb.u4[1]=tv6.y; xb.u4[2]=tv7.x; xb.u4[3]=tv7.y;
      c2 = __builtin_amdgcn_mfma_f32_16x16x32_bf16(pa[3], xb.s8, c2, 0,0,0);
    }
  }
  // ---- PU store (wave-private, complete over all 512 pos) ----
  long pb = ((long)b*OC_ + oc)*512;
  if (fq < 2){
    #pragma unroll
    for (int r=0;r<4;++r)
      PU[pb + (fq*4+r)*64 + w*16 + fr] = c2[r];
  }
  // ---- PS ----
  #pragma unroll
  for (int mk=1; mk<16; mk<<=1){
    tsl[0] += __shfl_xor(tsl[0], mk, 64);
    tsl[1] += __shfl_xor(tsl[1], mk, 64);
    tsl[2] += __shfl_xor(tsl[2], mk, 64);
    tsl[3] += __shfl_xor(tsl[3], mk, 64);
  }
  if (fr==0 && fq<2){
    SL[w][fq*4+0]=tsl[0]; SL[w][fq*4+1]=tsl[1];
    SL[w][fq*4+2]=tsl[2]; SL[w][fq*4+3]=tsl[3];
  }
  __syncthreads();
  if (t < 8)
    PS[((long)b*OC_ + oc)*8 + t] = SL[0][t]+SL[1][t]+SL[2][t]+SL[3][t];
}

// ---- reduce partials; updates=(U/S)@Wv; GRU(LDS-staged bf16 weights)+LN+MLP; next q ----
__global__ __launch_bounds__(512,2) void slot_update(
    const float* __restrict__ PU, const float* __restrict__ PS,
    float* __restrict__ slots,
    const float* __restrict__ WihT, const float* __restrict__ WhhT,
    const float* __restrict__ bih, const float* __restrict__ bhh,
    const float* __restrict__ W1, const float* __restrict__ b1,
    const float* __restrict__ W2, const float* __restrict__ b2,
    const float* __restrict__ lnffg, const float* __restrict__ lnffb,
    const float* __restrict__ lnsg, const float* __restrict__ lnsb,
    const float* __restrict__ Wv, const float* __restrict__ Wqk,
    u16* __restrict__ qbuf16, float* __restrict__ dout, int last){
  extern __shared__ char dsm[];
  u16* wih_l = (u16*)dsm;              // 24576 B
  u16* whh_l = (u16*)(dsm + 24576);    // 24576 B
  __shared__ float updL[K_][68];
  __shared__ float spL[K_][68];
  __shared__ float sfL[K_][68];
  __shared__ float hL[K_][132];
  int b = blockIdx.x, t = threadIdx.x;
  int i = t>>6, d = t&63;
  // stage GRU weights (bf16)
  {
    const float4* wa = (const float4*)WihT;
    const float4* wb = (const float4*)WhhT;
    #pragma unroll
    for (int k2=0;k2<6;++k2){
      int idx = t + k2*512;            // 0..3071
      float4 va = wa[idx], vb = wb[idx];
      ((u32*)wih_l)[idx*2]   = (u32)f2bf(va.x) | ((u32)f2bf(va.y)<<16);
      ((u32*)wih_l)[idx*2+1] = (u32)f2bf(va.z) | ((u32)f2bf(va.w)<<16);
      ((u32*)whh_l)[idx*2]   = (u32)f2bf(vb.x) | ((u32)f2bf(vb.y)<<16);
      ((u32*)whh_l)[idx*2+1] = (u32)f2bf(vb.z) | ((u32)f2bf(vb.w)<<16);
    }
  }
  float u=0.f;
  #pragma unroll
  for (int c=0;c<OC_;++c) u += PU[((long)b*OC_ + c)*512 + t];
  float S=0.f;
  #pragma unroll
  for (int c=0;c<OC_;++c) S += PS[((long)b*OC_ + c)*8 + i];
  float ut = u / S;
  float sp = slots[b*512 + t];
  sfL[i][d] = ut;
  spL[i][d] = sp;
  __syncthreads();
  float upd = 0.f;
  #pragma unroll 8
  for (int dd=0; dd<64; ++dd) upd += sfL[i][dd]*Wv[dd*64 + d];
  updL[i][d] = upd;
  __syncthreads();
  float gx0 = bih[d], gx1 = bih[64+d], gx2 = bih[128+d];
  float gh0 = bhh[d], gh1 = bhh[64+d], gh2 = bhh[128+d];
  #pragma unroll 8
  for (int dd=0; dd<64; ++dd){
    float uv = updL[i][dd];
    float sv = spL[i][dd];
    gx0 += uv*bf_lo((u32)wih_l[dd*192 + d]);
    gx1 += uv*bf_lo((u32)wih_l[dd*192 + 64 + d]);
    gx2 += uv*bf_lo((u32)wih_l[dd*192 + 128 + d]);
    gh0 += sv*bf_lo((u32)whh_l[dd*192 + d]);
    gh1 += sv*bf_lo((u32)whh_l[dd*192 + 64 + d]);
    gh2 += sv*bf_lo((u32)whh_l[dd*192 + 128 + d]);
  }
  float rg = 1.f/(1.f+__expf(-(gx0+gh0)));
  float zg = 1.f/(1.f+__expf(-(gx1+gh1)));
  float ng = tanhf(gx2 + rg*gh2);
  float sn = (1.f-zg)*ng + zg*sp;
  float m1 = wsum64(sn)*(1.f/64.f);
  float df = sn-m1;
  float vv = wsum64(df*df)*(1.f/64.f);
  float sf = df*rsqrtf(vv+EPS_LN)*lnffg[d] + lnffb[d];
  sfL[i][d] = sf;
  __syncthreads();
  float h0 = b1[d], h1 = b1[64+d];
  #pragma unroll 8
  for (int dd=0;dd<64;++dd){
    float sv = sfL[i][dd];
    h0 += sv*W1[dd*128 + d];
    h1 += sv*W1[dd*128 + 64 + d];
  }
  h0 = fmaxf(h0, 0.f); h1 = fmaxf(h1, 0.f);
  hL[i][d] = h0; hL[i][d+64] = h1;
  __syncthreads();
  float o = b2[d];
  #pragma unroll 8
  for (int hh=0; hh<128; ++hh) o += hL[i][hh]*W2[hh*64 + d];
  float out = sf + o;
  slots[b*512 + t] = out;
  if (last){
    dout[b*512 + t] = out;
  } else {
    float m2 = wsum64(out)*(1.f/64.f);
    float d2 = out-m2;
    float v2 = wsum64(d2*d2)*(1.f/64.f);
    float sq = d2*rsqrtf(v2+EPS_LN)*lnsg[d] + lnsb[d];
    updL[i][d] = sq;
    __syncthreads();
    float qt=0.f;
    #pragma unroll 8
    for (int dd=0;dd<64;++dd) qt += updL[i][dd]*Wqk[dd*64 + d];
    qbuf16[b*1024 + t] = f2bf(qt);
    qbuf16[b*1024 + 512 + t] = 0;
  }
}

extern "C" void kernel_launch(void* const* d_in, const int* in_sizes, int n_in,
                              void* d_out, int out_size, void* d_ws, size_t ws_size,
                              hipStream_t stream){
  const float* inp   = (const float*)d_in[0];
  const float* noise = (const float*)d_in[1];
  const float* mu    = (const float*)d_in[2];
  const float* sigma = (const float*)d_in[3];
  const float* Wq    = (const float*)d_in[4];
  const float* Wk    = (const float*)d_in[5];
  const float* Wv    = (const float*)d_in[6];
  const float* Wih   = (const float*)d_in[7];
  const float* Whh   = (const float*)d_in[8];
  const float* bih   = (const float*)d_in[9];
  const float* bhh   = (const float*)d_in[10];
  const float* W1    = (const float*)d_in[11];
  const float* b1    = (const float*)d_in[12];
  const float* W2    = (const float*)d_in[13];
  const float* b2    = (const float*)d_in[14];
  const float* lnig  = (const float*)d_in[15];
  const float* lnib  = (const float*)d_in[16];
  const float* lnsg  = (const float*)d_in[17];
  const float* lnsb  = (const float*)d_in[18];
  const float* lnffg = (const float*)d_in[19];
  const float* lnffb = (const float*)d_in[20];
  float* out = (float*)d_out;

  char* ws = (char*)d_ws;
  u16*   xhat   = (u16*)(ws);                      // 67108864 B
  u16*   qbuf16 = (u16*)(ws + 67108864);           // 262144 B
  float* slots  = (float*)(ws + 67371008);         // 262144 B
  float* PU     = (float*)(ws + 67633152);         // 128*8*512*4 = 2097152 B
  float* PS     = (float*)(ws + 69730304);         // 128*8*8*4   = 32768 B
  float* WihT   = (float*)(ws + 69763072);         // 49152 B
  float* WhhT   = (float*)(ws + 69812224);         // 49152 B
  float* Wqk    = (float*)(ws + 69861376);         // 16384 B -> ~69.9 MB total

  prep_t<<<64,256,0,stream>>>(Wih, Whh, Wq, Wk, WihT, WhhT, Wqk);
  slots_init<<<B_,512,0,stream>>>(noise, mu, sigma, Wqk, lnsg, lnsb, slots, qbuf16);
  for (int it=0; it<ITERS_; ++it){
    if (it==0)
      bigpass<1><<<dim3(OC_,B_),256,0,stream>>>(inp, xhat, qbuf16, lnig, lnib, PU, PS);
    else
      bigpass<0><<<dim3(OC_,B_),256,0,stream>>>(inp, xhat, qbuf16, lnig, lnib, PU, PS);
    slot_update<<<B_,512,49152,stream>>>(PU, PS, slots, WihT, WhhT, bih, bhh,
                                     W1, b1, W2, b2, lnffg, lnffb, lnsg, lnsb,
                                     Wv, Wqk, qbuf16, out, (it==ITERS_-1)?1:0);
  }
}

// Round 10
// 159.980 us; speedup vs baseline: 1.2556x; 1.1655x over previous
//
#include <hip/hip_runtime.h>
#include <hip/hip_bf16.h>

typedef unsigned int u32;
typedef unsigned short u16;
typedef __attribute__((ext_vector_type(8))) short short8;
typedef __attribute__((ext_vector_type(4))) float f32x4;
typedef __attribute__((ext_vector_type(2))) u32 u32x2;

#define B_      128
#define N_      4096
#define K_      8
#define ITERS_  3
#define OC_     8        // PU output chunks per batch
#define CPB_    4        // chunks per block
#define CHUNK   128
#define SCALE_  0.125f
#define EPS_A   1e-8f
#define EPS_LN  1e-5f

__device__ __forceinline__ float bf_lo(u32 u){ union{u32 v; float f;} x; x.v = u<<16; return x.f; }
__device__ __forceinline__ u16 f2bf(float f){
  union{float f; u32 v;} x; x.f = f;
  u32 v = x.v;
  return (u16)((v + 0x7fffu + ((v>>16)&1u))>>16);   // RNE
}
__device__ __forceinline__ float wsum64(float v){
  #pragma unroll
  for (int off=32; off; off>>=1) v += __shfl_xor(v, off, 64);
  return v;
}
__device__ __forceinline__ void gll16(const void* g, void* l){
  __builtin_amdgcn_global_load_lds(
      (const __attribute__((address_space(1))) void*)g,
      (__attribute__((address_space(3))) void*)l, 16, 0, 0);
}

// ---- one-time prep: transpose GRU weights; Wqk = Wq @ Wk^T ----
__global__ void prep_t(const float* __restrict__ Wih, const float* __restrict__ Whh,
                       const float* __restrict__ Wq,  const float* __restrict__ Wk,
                       float* __restrict__ WihT, float* __restrict__ WhhT,
                       float* __restrict__ Wqk){
  int t = threadIdx.x;
  if (blockIdx.x < 48){
    int idx = blockIdx.x*256 + t;            // 12288 = 192*64
    int g = idx>>6, d = idx&63;
    WihT[d*192+g] = Wih[idx];
    WhhT[d*192+g] = Whh[idx];
  } else {
    __shared__ float WkL[64*65];
    int bi = blockIdx.x - 48;                // 0..15
    #pragma unroll
    for (int k=0;k<16;++k){
      int idx = t + k*256;
      int d = idx>>6, m = idx&63;
      WkL[m*65+d] = Wk[idx];
    }
    __syncthreads();
    int a = bi*4 + (t>>6), d = t&63;
    float acc = 0.f;
    #pragma unroll 8
    for (int m=0;m<64;++m) acc += Wq[a*64+m]*WkL[m*65+d];
    Wqk[a*64+d] = acc;
  }
}

// ---- slots0 = mu + sigma*noise ; qt = LN(slots0)@Wqk (bf16, padded 16 rows) ----
__global__ __launch_bounds__(512) void slots_init(
    const float* __restrict__ noise, const float* __restrict__ mu, const float* __restrict__ sigma,
    const float* __restrict__ Wqk,
    const float* __restrict__ lnsg, const float* __restrict__ lnsb,
    float* __restrict__ slots, u16* __restrict__ qbuf16){
  int b = blockIdx.x, t = threadIdx.x;
  int i = t>>6, d = t&63;
  __shared__ float svL[K_][68];
  float s0 = mu[d] + sigma[d]*noise[b*512 + t];
  slots[b*512 + t] = s0;
  float m  = wsum64(s0) * (1.f/64.f);
  float df = s0 - m;
  float vv = wsum64(df*df) * (1.f/64.f);
  float sv = df * rsqrtf(vv + EPS_LN) * lnsg[d] + lnsb[d];
  svL[i][d] = sv;
  __syncthreads();
  float qt = 0.f;
  #pragma unroll 8
  for (int dd=0; dd<64; ++dd) qt += svL[i][dd] * Wqk[dd*64 + d];
  qbuf16[b*1024 + t] = f2bf(qt);
  qbuf16[b*1024 + 512 + t] = 0;          // pad rows 8..15
}

// ---- pipelined bigpass. xhat is stored as per-tile LDS IMAGES (16 KB each),
// so non-fused staging is a linear global_load_lds copy. Subtile layout for
// elem (p,d): byte = (p>>5)<<12 | (d>>4)<<10 | ((p>>2)&1)<<9 | ((p>>3)&3)<<7
//                  | (p&3)<<5 | (d&15)*2   (verified on HW in R9)
template<int FUSED>
__global__ __launch_bounds__(256,4) void bigpass(
    const float* __restrict__ inp, u16* __restrict__ xhat,
    const u16* __restrict__ qbuf16,
    const float* __restrict__ lng, const float* __restrict__ lnb,
    float* __restrict__ PU, float* __restrict__ PS){
  int b = blockIdx.y, oc = blockIdx.x, t = threadIdx.x;
  int w = t>>6, lane = t&63;
  int fr = lane&15, fq = lane>>4;

  // LDS: [0,32768) xs dbuf 2x16KB ; [32768,34816) qA ; [34816,38912) abuf
  __shared__ __align__(16) char smem[38912];
  char* qA   = smem + 32768;
  char* abuf = smem + 34816;
  __shared__ float SL[4][8];
  u32 smb = (u32)(size_t)smem;

  if (t < 128){
    uint4 v = ((const uint4*)(qbuf16 + b*1024))[t];
    int row = t>>3;
    *(uint4*)(qA + ((t*16) ^ ((row&7)<<4))) = v;
  }
  long tile0 = ((long)b*OC_ + oc)*CPB_;
  long base_pos = (long)b*N_ + (long)oc*(CPB_*CHUNK);

  short8 qf0, qf1;
  f32x4 c2 = (f32x4){0.f,0.f,0.f,0.f};
  float tsl[4] = {0.f,0.f,0.f,0.f};

  float lg[16], lb[16];
  if (FUSED){
    int q = t&3;
    #pragma unroll
    for (int e=0;e<16;++e){ lg[e] = lng[q*16+e]; lb[e] = lnb[q*16+e]; }
  }
  if (!FUSED){
    // prologue: stage chunk 0 into buf 0 (async, drains at first barrier)
    const char* gsrc = (const char*)xhat + (tile0<<14) + w*4096 + lane*16;
    char* ldst = smem + w*4096;
    #pragma unroll
    for (int j=0;j<4;++j) gll16(gsrc + j*1024, ldst + j*1024);
  }

  #pragma unroll
  for (int cc=0; cc<CPB_; ++cc){
    int buf = cc&1;
    if (FUSED){
      // LN from f32 inputs into LDS image (2 passes of 64 rows)
      #pragma unroll
      for (int p2=0;p2<2;++p2){
        int r = p2*64 + (t>>2), q = t&3;
        const float4* xr = (const float4*)(inp + (base_pos + (long)cc*CHUNK + r)*64 + q*16);
        float xv[16]; float s=0.f, sq=0.f;
        #pragma unroll
        for (int c=0;c<4;++c){
          float4 f = xr[c];
          xv[c*4+0]=f.x; xv[c*4+1]=f.y; xv[c*4+2]=f.z; xv[c*4+3]=f.w;
          s  += f.x+f.y+f.z+f.w;
          sq += f.x*f.x+f.y*f.y+f.z*f.z+f.w*f.w;
        }
        s  += __shfl_xor(s,1,64);  s  += __shfl_xor(s,2,64);
        sq += __shfl_xor(sq,1,64); sq += __shfl_xor(sq,2,64);
        float mean = s*(1.f/64.f);
        float inv  = rsqrtf(sq*(1.f/64.f) - mean*mean + EPS_LN);
        u32 pk[8];
        #pragma unroll
        for (int e=0;e<8;++e){
          float a0 = (xv[e*2]  -mean)*inv*lg[e*2]   + lb[e*2];
          float a1 = (xv[e*2+1]-mean)*inv*lg[e*2+1] + lb[e*2+1];
          pk[e] = (u32)f2bf(a0) | ((u32)f2bf(a1)<<16);
        }
        uint4 v0; v0.x=pk[0]; v0.y=pk[1]; v0.z=pk[2]; v0.w=pk[3];
        uint4 v1; v1.x=pk[4]; v1.y=pk[5]; v1.z=pk[6]; v1.w=pk[7];
        int byte0 = ((r>>5)<<12) | (q<<10) | (((r>>2)&1)<<9) | (((r>>3)&3)<<7) | ((r&3)<<5);
        *(uint4*)(smem + buf*16384 + byte0)      = v0;
        *(uint4*)(smem + buf*16384 + byte0 + 16) = v1;
      }
    }
    __syncthreads();   // bar A: buf image ready; prev-chunk LDS readers released
    if (FUSED){
      // write the tile image to global (linear, coalesced both sides)
      const uint4* ls = (const uint4*)(smem + buf*16384);
      uint4* gim = (uint4*)((char*)xhat + ((tile0+cc)<<14));
      #pragma unroll
      for (int j=0;j<4;++j) gim[t + j*256] = ls[t + j*256];
    } else if (cc+1 < CPB_){
      // async prefetch next chunk into the other buffer
      const char* gsrc = (const char*)xhat + ((tile0+cc+1)<<14) + w*4096 + lane*16;
      char* ldst = smem + (buf^1)*16384 + w*4096;
      #pragma unroll
      for (int j=0;j<4;++j) gll16(gsrc + j*1024, ldst + j*1024);
    }
    if (cc==0){
      qf0 = *(const short8*)(qA + ((fr*128 +  0 + fq*16) ^ ((fr&7)<<4)));
      qf1 = *(const short8*)(qA + ((fr*128 + 64 + fq*16) ^ ((fr&7)<<4)));
    }
    // ---- phase 1: dots[16 slots][32 pos per wave] ----
    f32x4 c1[2];
    #pragma unroll
    for (int nt=0;nt<2;++nt){
      c1[nt] = (f32x4){0.f,0.f,0.f,0.f};
      #pragma unroll
      for (int kk=0;kk<2;++kk){
        int byte = (w<<12) | ((kk*2+(fq>>1))<<10) | (((fr>>2)&1)<<9)
                 | ((nt*2+(fr>>3))<<7) | ((fr&3)<<5) | ((fq&1)<<4);
        short8 xf = *(const short8*)(smem + buf*16384 + byte);
        c1[nt] = __builtin_amdgcn_mfma_f32_16x16x32_bf16(kk?qf1:qf0, xf, c1[nt], 0,0,0);
      }
    }
    // softmax over slots + abuf write (attn [slot][pos], slot-row swizzled)
    #pragma unroll
    for (int nt=0;nt<2;++nt){
      float d0 = c1[nt][0]*SCALE_, d1 = c1[nt][1]*SCALE_;
      float d2 = c1[nt][2]*SCALE_, d3 = c1[nt][3]*SCALE_;
      float m = fmaxf(fmaxf(d0,d1), fmaxf(d2,d3));
      m = fmaxf(m, __shfl_xor(m, 16, 64));
      float e0 = __expf(d0-m), e1 = __expf(d1-m), e2 = __expf(d2-m), e3 = __expf(d3-m);
      float sl = e0+e1+e2+e3;
      float inv = 1.f/(sl + __shfl_xor(sl, 16, 64));
      float a0 = e0*inv + EPS_A, a1 = e1*inv + EPS_A;
      float a2 = e2*inv + EPS_A, a3 = e3*inv + EPS_A;
      tsl[0]+=a0; tsl[1]+=a1; tsl[2]+=a2; tsl[3]+=a3;
      int pos2 = w*64 + nt*32 + fr*2;
      #pragma unroll
      for (int r=0;r<4;++r){
        int slot = fq*4 + r;
        float av = (r==0)?a0:((r==1)?a1:((r==2)?a2:a3));
        int byteA = ((slot<<8) + pos2) ^ ((slot&7)<<4);
        *(u16*)(abuf + byteA) = f2bf(av);
      }
    }
    __syncthreads();   // bar B: abuf complete
    // ---- phase 2: wave w owns d-tile w; accumulate over 128 pos ----
    {
      u32 va = smb + buf*16384 + (w<<10) + (fq<<7) + (fr<<1);
      u32x2 tv0,tv1,tv2,tv3,tv4,tv5,tv6,tv7;
      asm volatile("ds_read_b64_tr_b16 %0, %1 offset:0"     : "=v"(tv0) : "v"(va));
      asm volatile("ds_read_b64_tr_b16 %0, %1 offset:512"   : "=v"(tv1) : "v"(va));
      asm volatile("ds_read_b64_tr_b16 %0, %1 offset:4096"  : "=v"(tv2) : "v"(va));
      asm volatile("ds_read_b64_tr_b16 %0, %1 offset:4608"  : "=v"(tv3) : "v"(va));
      asm volatile("ds_read_b64_tr_b16 %0, %1 offset:8192"  : "=v"(tv4) : "v"(va));
      asm volatile("ds_read_b64_tr_b16 %0, %1 offset:8704"  : "=v"(tv5) : "v"(va));
      asm volatile("ds_read_b64_tr_b16 %0, %1 offset:12288" : "=v"(tv6) : "v"(va));
      asm volatile("ds_read_b64_tr_b16 %0, %1 offset:12800" : "=v"(tv7) : "v"(va));
      short8 pa[4];
      #pragma unroll
      for (int k2=0;k2<4;++k2){
        int byteP = (fr<<8) + ((k2*64 + fq*16) ^ ((fr&7)<<4));
        pa[k2] = *(const short8*)(abuf + byteP);
      }
      asm volatile("s_waitcnt lgkmcnt(0)" ::: "memory");
      __builtin_amdgcn_sched_barrier(0);
      union { short8 s8; u32 u4[4]; } xb;
      xb.u4[0]=tv0.x; xb.u4[1]=tv0.y; xb.u4[2]=tv1.x; xb.u4[3]=tv1.y;
      c2 = __builtin_amdgcn_mfma_f32_16x16x32_bf16(pa[0], xb.s8, c2, 0,0,0);
      xb.u4[0]=tv2.x; xb.u4[1]=tv2.y; xb.u4[2]=tv3.x; xb.u4[3]=tv3.y;
      c2 = __builtin_amdgcn_mfma_f32_16x16x32_bf16(pa[1], xb.s8, c2, 0,0,0);
      xb.u4[0]=tv4.x; xb.u4[1]=tv4.y; xb.u4[2]=tv5.x; xb.u4[3]=tv5.y;
      c2 = __builtin_amdgcn_mfma_f32_16x16x32_bf16(pa[2], xb.s8, c2, 0,0,0);
      xb.u4[0]=tv6.x; xb.u4[1]=tv6.y; xb.u4[2]=tv7.x; xb.u4[3]=tv7.y;
      c2 = __builtin_amdgcn_mfma_f32_16x16x32_bf16(pa[3], xb.s8, c2, 0,0,0);
    }
  }
  // ---- PU store (wave-private, complete over all 512 pos) ----
  long pb = ((long)b*OC_ + oc)*512;
  if (fq < 2){
    #pragma unroll
    for (int r=0;r<4;++r)
      PU[pb + (fq*4+r)*64 + w*16 + fr] = c2[r];
  }
  // ---- PS ----
  #pragma unroll
  for (int mk=1; mk<16; mk<<=1){
    tsl[0] += __shfl_xor(tsl[0], mk, 64);
    tsl[1] += __shfl_xor(tsl[1], mk, 64);
    tsl[2] += __shfl_xor(tsl[2], mk, 64);
    tsl[3] += __shfl_xor(tsl[3], mk, 64);
  }
  if (fr==0 && fq<2){
    SL[w][fq*4+0]=tsl[0]; SL[w][fq*4+1]=tsl[1];
    SL[w][fq*4+2]=tsl[2]; SL[w][fq*4+3]=tsl[3];
  }
  __syncthreads();
  if (t < 8)
    PS[((long)b*OC_ + oc)*8 + t] = SL[0][t]+SL[1][t]+SL[2][t]+SL[3][t];
}

// ---- reduce partials; updates=(U/S)@Wv; GRU (two-stage fp32 LDS weights);
//      LN + MLP; next q-tilde ----
__global__ __launch_bounds__(512,2) void slot_update(
    const float* __restrict__ PU, const float* __restrict__ PS,
    float* __restrict__ slots,
    const float* __restrict__ WihT, const float* __restrict__ WhhT,
    const float* __restrict__ bih, const float* __restrict__ bhh,
    const float* __restrict__ W1, const float* __restrict__ b1,
    const float* __restrict__ W2, const float* __restrict__ b2,
    const float* __restrict__ lnffg, const float* __restrict__ lnffb,
    const float* __restrict__ lnsg, const float* __restrict__ lnsb,
    const float* __restrict__ Wv, const float* __restrict__ Wqk,
    u16* __restrict__ qbuf16, float* __restrict__ dout, int last){
  extern __shared__ float wls[];       // 49152 B (one 192x64 fp32 matrix)
  __shared__ float updL[K_][68];
  __shared__ float spL[K_][68];
  __shared__ float sfL[K_][68];
  __shared__ float hL[K_][132];
  int b = blockIdx.x, t = threadIdx.x;
  int i = t>>6, d = t&63;
  float u=0.f;
  #pragma unroll
  for (int c=0;c<OC_;++c) u += PU[((long)b*OC_ + c)*512 + t];
  float S=0.f;
  #pragma unroll
  for (int c=0;c<OC_;++c) S += PS[((long)b*OC_ + c)*8 + i];
  float ut = u / S;
  float sp = slots[b*512 + t];
  sfL[i][d] = ut;
  spL[i][d] = sp;
  {
    const float4* wa = (const float4*)WihT;
    #pragma unroll
    for (int k2=0;k2<6;++k2){ int idx = t + k2*512; ((float4*)wls)[idx] = wa[idx]; }
  }
  __syncthreads();
  float upd = 0.f;
  #pragma unroll 8
  for (int dd=0; dd<64; ++dd) upd += sfL[i][dd]*Wv[dd*64 + d];
  updL[i][d] = upd;
  __syncthreads();
  float gx0 = bih[d], gx1 = bih[64+d], gx2 = bih[128+d];
  #pragma unroll 8
  for (int dd=0; dd<64; ++dd){
    float uv = updL[i][dd];
    gx0 += uv*wls[dd*192 + d];
    gx1 += uv*wls[dd*192 + 64 + d];
    gx2 += uv*wls[dd*192 + 128 + d];
  }
  __syncthreads();        // all wih reads done
  {
    const float4* wb = (const float4*)WhhT;
    #pragma unroll
    for (int k2=0;k2<6;++k2){ int idx = t + k2*512; ((float4*)wls)[idx] = wb[idx]; }
  }
  __syncthreads();
  float gh0 = bhh[d], gh1 = bhh[64+d], gh2 = bhh[128+d];
  #pragma unroll 8
  for (int dd=0; dd<64; ++dd){
    float sv = spL[i][dd];
    gh0 += sv*wls[dd*192 + d];
    gh1 += sv*wls[dd*192 + 64 + d];
    gh2 += sv*wls[dd*192 + 128 + d];
  }
  float rg = 1.f/(1.f+__expf(-(gx0+gh0)));
  float zg = 1.f/(1.f+__expf(-(gx1+gh1)));
  float ng = tanhf(gx2 + rg*gh2);
  float sn = (1.f-zg)*ng + zg*sp;
  float m1 = wsum64(sn)*(1.f/64.f);
  float df = sn-m1;
  float vv = wsum64(df*df)*(1.f/64.f);
  float sf = df*rsqrtf(vv+EPS_LN)*lnffg[d] + lnffb[d];
  sfL[i][d] = sf;
  __syncthreads();
  float h0 = b1[d], h1 = b1[64+d];
  #pragma unroll 8
  for (int dd=0;dd<64;++dd){
    float sv = sfL[i][dd];
    h0 += sv*W1[dd*128 + d];
    h1 += sv*W1[dd*128 + 64 + d];
  }
  h0 = fmaxf(h0, 0.f); h1 = fmaxf(h1, 0.f);
  hL[i][d] = h0; hL[i][d+64] = h1;
  __syncthreads();
  float o = b2[d];
  #pragma unroll 8
  for (int hh=0; hh<128; ++hh) o += hL[i][hh]*W2[hh*64 + d];
  float out = sf + o;
  slots[b*512 + t] = out;
  if (last){
    dout[b*512 + t] = out;
  } else {
    float m2 = wsum64(out)*(1.f/64.f);
    float d2 = out-m2;
    float v2 = wsum64(d2*d2)*(1.f/64.f);
    float sq = d2*rsqrtf(v2+EPS_LN)*lnsg[d] + lnsb[d];
    updL[i][d] = sq;
    __syncthreads();
    float qt=0.f;
    #pragma unroll 8
    for (int dd=0;dd<64;++dd) qt += updL[i][dd]*Wqk[dd*64 + d];
    qbuf16[b*1024 + t] = f2bf(qt);
    qbuf16[b*1024 + 512 + t] = 0;
  }
}

extern "C" void kernel_launch(void* const* d_in, const int* in_sizes, int n_in,
                              void* d_out, int out_size, void* d_ws, size_t ws_size,
                              hipStream_t stream){
  const float* inp   = (const float*)d_in[0];
  const float* noise = (const float*)d_in[1];
  const float* mu    = (const float*)d_in[2];
  const float* sigma = (const float*)d_in[3];
  const float* Wq    = (const float*)d_in[4];
  const float* Wk    = (const float*)d_in[5];
  const float* Wv    = (const float*)d_in[6];
  const float* Wih   = (const float*)d_in[7];
  const float* Whh   = (const float*)d_in[8];
  const float* bih   = (const float*)d_in[9];
  const float* bhh   = (const float*)d_in[10];
  const float* W1    = (const float*)d_in[11];
  const float* b1    = (const float*)d_in[12];
  const float* W2    = (const float*)d_in[13];
  const float* b2    = (const float*)d_in[14];
  const float* lnig  = (const float*)d_in[15];
  const float* lnib  = (const float*)d_in[16];
  const float* lnsg  = (const float*)d_in[17];
  const float* lnsb  = (const float*)d_in[18];
  const float* lnffg = (const float*)d_in[19];
  const float* lnffb = (const float*)d_in[20];
  float* out = (float*)d_out;

  char* ws = (char*)d_ws;
  u16*   xhat   = (u16*)(ws);                      // 67108864 B (tile images)
  u16*   qbuf16 = (u16*)(ws + 67108864);           // 262144 B
  float* slots  = (float*)(ws + 67371008);         // 262144 B
  float* PU     = (float*)(ws + 67633152);         // 128*8*512*4 = 2097152 B
  float* PS     = (float*)(ws + 69730304);         // 128*8*8*4   = 32768 B
  float* WihT   = (float*)(ws + 69763072);         // 49152 B
  float* WhhT   = (float*)(ws + 69812224);         // 49152 B
  float* Wqk    = (float*)(ws + 69861376);         // 16384 B -> ~69.9 MB total

  prep_t<<<64,256,0,stream>>>(Wih, Whh, Wq, Wk, WihT, WhhT, Wqk);
  slots_init<<<B_,512,0,stream>>>(noise, mu, sigma, Wqk, lnsg, lnsb, slots, qbuf16);
  for (int it=0; it<ITERS_; ++it){
    if (it==0)
      bigpass<1><<<dim3(OC_,B_),256,0,stream>>>(inp, xhat, qbuf16, lnig, lnib, PU, PS);
    else
      bigpass<0><<<dim3(OC_,B_),256,0,stream>>>(inp, xhat, qbuf16, lnig, lnib, PU, PS);
    slot_update<<<B_,512,49152,stream>>>(PU, PS, slots, WihT, WhhT, bih, bhh,
                                     W1, b1, W2, b2, lnffg, lnffb, lnsg, lnsb,
                                     Wv, Wqk, qbuf16, out, (it==ITERS_-1)?1:0);
  }
}